// Round 5
// baseline (645.212 us; speedup 1.0000x reference)
//
#include <hip/hip_runtime.h>

typedef unsigned short u16;
typedef short bf16x8 __attribute__((ext_vector_type(8)));
typedef float f32x4 __attribute__((ext_vector_type(4)));
typedef unsigned short u16x8 __attribute__((ext_vector_type(8)));

#define GLL16(gp, lp) __builtin_amdgcn_global_load_lds( \
    (__attribute__((address_space(1))) const unsigned int*)(gp), \
    (__attribute__((address_space(3))) unsigned int*)(lp), 16, 0, 0)

static __device__ __forceinline__ u16 f2bf(float f){
  unsigned u = __builtin_bit_cast(unsigned, f);
  u += 0x7fffu + ((u >> 16) & 1u);   // RNE
  return (u16)(u >> 16);
}

// ---------------- transpose + convert: dst[b][c][r] = bf16(src[b][r][c]), r zero-padded to Rpad
__global__ void transpose_f32(const float* __restrict__ src, u16* __restrict__ dst,
                              int R, int C, int Rpad, long sB, long dB){
  __shared__ u16 tile[32][33];
  const int b = blockIdx.z;
  src += (long)b*sB; dst += (long)b*dB;
  const int r0 = blockIdx.x*32, c0 = blockIdx.y*32;
  const int j = threadIdx.x & 31, i0 = threadIdx.x >> 5;
  #pragma unroll
  for (int ii=0; ii<32; ii+=8){
    int r = r0+i0+ii, c = c0+j;
    u16 v = 0;
    if (r < R && c < C) v = f2bf(src[(long)r*C + c]);
    tile[i0+ii][j] = v;
  }
  __syncthreads();
  #pragma unroll
  for (int ii=0; ii<32; ii+=8){
    int c = c0+i0+ii, r = r0+j;
    if (c < C && r < Rpad) dst[(long)c*Rpad + r] = tile[j][i0+ii];
  }
}

__global__ void transpose_u16(const u16* __restrict__ src, u16* __restrict__ dst,
                              int R, int C, int Rpad, long sB, long dB){
  __shared__ u16 tile[32][33];
  const int b = blockIdx.z;
  src += (long)b*sB; dst += (long)b*dB;
  const int r0 = blockIdx.x*32, c0 = blockIdx.y*32;
  const int j = threadIdx.x & 31, i0 = threadIdx.x >> 5;
  #pragma unroll
  for (int ii=0; ii<32; ii+=8){
    int r = r0+i0+ii, c = c0+j;
    u16 v = 0;
    if (r < R && c < C) v = src[(long)r*C + c];
    tile[i0+ii][j] = v;
  }
  __syncthreads();
  #pragma unroll
  for (int ii=0; ii<32; ii+=8){
    int c = c0+i0+ii, r = r0+j;
    if (c < C && r < Rpad) dst[(long)c*Rpad + r] = tile[j][i0+ii];
  }
}

// ---------------- G1: edges = H@ori (M=8000 N=256 K=2048pad), BK=64 super-iters, emits HT
__global__ __launch_bounds__(256,1) void g1_kernel(
    const float* __restrict__ Hm, const u16* __restrict__ oriT,
    u16* __restrict__ edges, u16* __restrict__ HT){
  __shared__ u16 As[2][2][64*32];
  __shared__ u16 Bs[2][2][256*32];
  __shared__ u16 At[2][2][32*66];
  const int b = blockIdx.y, bm = blockIdx.x*64;
  const int tid = threadIdx.x;
  const int w = tid>>6, quad = (tid&63)>>4, l16 = tid&15;
  const int wn = w*64;
  const float* Ab = Hm + (size_t)b*8000*2000 + (size_t)bm*2000;
  const u16*  Bb = oriT + (size_t)b*256*2048;
  u16* HTb = HT + (size_t)b*2048*8000;

  float4 pa[4];
  auto loadA = [&](int s){                       // 64 rows x 64 k (fp32) -> regs
    const int k0 = s*64;
    #pragma unroll
    for (int i=0;i<4;i++){
      int idx = i*256+tid, row = idx>>4, c4 = (idx&15)*4;
      bool ok = (k0+c4 < 2000);
      pa[i] = ok ? *(const float4*)(Ab + (size_t)row*2000 + k0+c4) : make_float4(0.f,0.f,0.f,0.f);
    }
  };
  auto storeA = [&](int s){
    const int buf = s&1;
    #pragma unroll
    for (int i=0;i<4;i++){
      int idx = i*256+tid, row = idx>>4, c4 = (idx&15)*4;
      int sub = c4>>5, cc = c4&31;
      ushort4 o; o.x=f2bf(pa[i].x); o.y=f2bf(pa[i].y); o.z=f2bf(pa[i].z); o.w=f2bf(pa[i].w);
      *(ushort4*)(&As[buf][sub][row*32 + cc]) = o;
      At[buf][sub][(cc+0)*66 + row] = o.x;
      At[buf][sub][(cc+1)*66 + row] = o.y;
      At[buf][sub][(cc+2)*66 + row] = o.z;
      At[buf][sub][(cc+3)*66 + row] = o.w;
    }
  };
  auto stageB = [&](int s){
    const int buf = s&1, k0 = s*64;
    #pragma unroll
    for (int sub=0; sub<2; sub++){
      #pragma unroll
      for (int i=0;i<4;i++){
        int idx = i*256+tid, row = idx>>2, c8 = (idx&3)*8;
        GLL16(Bb + (size_t)row*2048 + k0 + sub*32 + c8, &Bs[buf][sub][(i*256 + w*64)*8]);
      }
    }
  };

  f32x4 acc[4][4];
  #pragma unroll
  for (int i=0;i<4;i++)
    #pragma unroll
    for (int j=0;j<4;j++) acc[i][j] = (f32x4){0.f,0.f,0.f,0.f};

  loadA(0); stageB(0);
  for (int s=0; s<32; s++){
    storeA(s);
    __syncthreads();
    if (s+1 < 32){ stageB(s+1); loadA(s+1); }
    const int buf = s&1, k0 = s*64;
    #pragma unroll
    for (int sub=0; sub<2; sub++){
      { // HT write: 32(k) x 64(m)
        int kk = tid>>3, m0 = (tid&7)*8;
        u16x8 v = *(const u16x8*)(&At[buf][sub][kk*66 + m0]);
        *(u16x8*)(HTb + (size_t)(k0 + sub*32 + kk)*8000 + bm + m0) = v;
      }
      bf16x8 af[4], bf[4];
      #pragma unroll
      for (int mi=0;mi<4;mi++) af[mi] = *(const bf16x8*)(&As[buf][sub][(mi*16+l16)*32 + quad*8]);
      #pragma unroll
      for (int ni=0;ni<4;ni++) bf[ni] = *(const bf16x8*)(&Bs[buf][sub][(wn+ni*16+l16)*32 + quad*8]);
      #pragma unroll
      for (int mi=0;mi<4;mi++)
        #pragma unroll
        for (int ni=0;ni<4;ni++)
          acc[mi][ni] = __builtin_amdgcn_mfma_f32_16x16x32_bf16(af[mi], bf[ni], acc[mi][ni], 0,0,0);
    }
  }
  #pragma unroll
  for (int mi=0;mi<4;mi++){
    #pragma unroll
    for (int r=0;r<4;r++){
      int gm = bm + mi*16 + quad*4 + r;
      u16* dst = edges + ((size_t)b*8000 + gm)*256;
      #pragma unroll
      for (int ni=0;ni<4;ni++) dst[wn + ni*16 + l16] = f2bf(acc[mi][ni][r]);
    }
  }
}

// ---------------- M12: fused per-edge MLP. EF[m,d] = sum_t ed[m,t]*(relu(edges@W1_t+b1_t)@W2_t + b2_t)
__global__ __launch_bounds__(256,1) void m12_kernel(
    const u16* __restrict__ edges, const u16* __restrict__ W1T, const u16* __restrict__ W2T,
    const float* __restrict__ b1, const float* __restrict__ b2,
    const float* __restrict__ edist, u16* __restrict__ EF){
  __shared__ u16 Es[8][64*32];     // edges tile, K-sub-major (k=d_in)
  __shared__ u16 Hs[4][64*32];     // h_t tile, K-sub-major (k=hid), overwritten per t
  __shared__ u16 Ws1[2][128*32];
  __shared__ u16 Ws2[2][256*32];
  __shared__ float eds[64*5], b1s[640], b2s[1280];
  const int bm = blockIdx.x*64;    // global edge-row base (b*8000+e flattened)
  const int tid = threadIdx.x;
  const int w = tid>>6, quad = (tid&63)>>4, l16 = tid&15;
  const int r0 = w*16;             // this wave's 16-row slice

  for (int i=tid;i<320;i+=256)  eds[i] = edist[(size_t)bm*5 + i];
  for (int i=tid;i<640;i+=256)  b1s[i] = b1[i];
  for (int i=tid;i<1280;i+=256) b2s[i] = b2[i];
  { // stage Es: 64 rows x 256 k
    int row = tid>>2, cp = tid&3;
    const u16* src = edges + ((size_t)(bm+row))*256 + cp*64;
    #pragma unroll
    for (int j=0;j<8;j++){
      u16x8 v = *(const u16x8*)(src + j*8);
      *(u16x8*)(&Es[cp*2 + (j>>2)][row*32 + (j&3)*8]) = v;
    }
  }

  auto stageW1 = [&](int t, int ks){
    const int buf = ks&1;
    int row = tid>>1, p = tid&1;
    const u16* src = W1T + ((size_t)(t*128+row))*256 + ks*32;
    #pragma unroll
    for (int j=0;j<2;j++){
      int ch = p*2 + j;
      u16x8 v = *(const u16x8*)(src + ch*8);
      *(u16x8*)(&Ws1[buf][row*32 + ch*8]) = v;
    }
  };
  auto stageW2 = [&](int t, int ks){
    const int buf = ks&1;
    int row = tid;
    const u16* src = W2T + ((size_t)(t*256+row))*128 + ks*32;
    #pragma unroll
    for (int j=0;j<4;j++){
      u16x8 v = *(const u16x8*)(src + j*8);
      *(u16x8*)(&Ws2[buf][row*32 + j*8]) = v;
    }
  };

  f32x4 acc2[16];
  #pragma unroll
  for (int i=0;i<16;i++) acc2[i] = (f32x4){0.f,0.f,0.f,0.f};

  for (int t=0; t<5; t++){
    // ---- m1: h = relu(E @ W1_t + b1) * ed   (per wave: 16 rows x 128)
    f32x4 acc1[8];
    #pragma unroll
    for (int i=0;i<8;i++) acc1[i] = (f32x4){0.f,0.f,0.f,0.f};
    stageW1(t, 0);
    for (int ks=0; ks<8; ks++){
      __syncthreads();
      if (ks+1 < 8) stageW1(t, ks+1);
      const int buf = ks&1;
      bf16x8 af = *(const bf16x8*)(&Es[ks][(r0+l16)*32 + quad*8]);
      #pragma unroll
      for (int ni=0;ni<8;ni++){
        bf16x8 bf = *(const bf16x8*)(&Ws1[buf][(ni*16+l16)*32 + quad*8]);
        acc1[ni] = __builtin_amdgcn_mfma_f32_16x16x32_bf16(af, bf, acc1[ni], 0,0,0);
      }
    }
    // h -> Hs (A-layout), relu+bias+gate
    #pragma unroll
    for (int ni=0;ni<8;ni++){
      int col = ni*16 + l16;
      #pragma unroll
      for (int r=0;r<4;r++){
        int row = r0 + quad*4 + r;
        float v = fmaxf(acc1[ni][r] + b1s[t*128+col], 0.f) * eds[row*5+t];
        Hs[ni>>1][row*32 + (ni&1)*16 + l16] = f2bf(v);
      }
    }
    // ---- m2: acc2 += h @ W2_t   (per wave: 16 rows x 256)
    stageW2(t, 0);
    for (int ks=0; ks<4; ks++){
      __syncthreads();
      if (ks+1 < 4) stageW2(t, ks+1);
      const int buf = ks&1;
      bf16x8 af = *(const bf16x8*)(&Hs[ks][(r0+l16)*32 + quad*8]);
      #pragma unroll
      for (int ni=0;ni<16;ni++){
        bf16x8 bf = *(const bf16x8*)(&Ws2[buf][(ni*16+l16)*32 + quad*8]);
        acc2[ni] = __builtin_amdgcn_mfma_f32_16x16x32_bf16(af, bf, acc2[ni], 0,0,0);
      }
    }
  }
  // ---- epilogue: EF = acc2 + sum_t ed*b2
  #pragma unroll
  for (int r=0;r<4;r++){
    int row = r0 + quad*4 + r;
    float e0=eds[row*5+0], e1=eds[row*5+1], e2=eds[row*5+2], e3=eds[row*5+3], e4=eds[row*5+4];
    u16* dst = EF + ((size_t)(bm+row))*256;
    #pragma unroll
    for (int ni=0;ni<16;ni++){
      int d = ni*16 + l16;
      float bias = e0*b2s[d] + e1*b2s[256+d] + e2*b2s[512+d] + e3*b2s[768+d] + e4*b2s[1024+d];
      dst[d] = f2bf(acc2[ni][r] + bias);
    }
  }
}

// ---------------- G3: part[b,ks][m,d] = sum_{e slice} HT[b,m,e]*EFt[b,d,e], BK=64 supers
__global__ __launch_bounds__(256,2) void g3_kernel(
    const u16* __restrict__ HT, const u16* __restrict__ EFt, float* __restrict__ part){
  __shared__ u16 As[2][2][64*32];
  __shared__ u16 Bs[2][2][256*32];
  const int bm = blockIdx.x*64, ks = blockIdx.y, b = blockIdx.z;
  const int tid = threadIdx.x;
  const int w = tid>>6, quad = (tid&63)>>4, l16 = tid&15;
  const int wn = w*64;
  const u16* Ab = HT + (size_t)b*2048*8000 + (size_t)bm*8000;
  const u16* Bb = EFt + (size_t)b*256*8000;
  const int r32[5] = {0,64,128,192,250};       // 32-k unit boundaries (all even)
  const int s0 = r32[ks]>>1, s1 = r32[ks+1]>>1;

  auto stage = [&](int s){
    const int buf = s&1, k0 = s*64;
    #pragma unroll
    for (int sub=0; sub<2; sub++){
      {
        int row = tid>>2, c8 = (tid&3)*8;
        GLL16(Ab + (size_t)row*8000 + k0 + sub*32 + c8, &As[buf][sub][(w*64)*8]);
      }
      #pragma unroll
      for (int i=0;i<4;i++){
        int idx = i*256+tid, row = idx>>2, c8 = (idx&3)*8;
        GLL16(Bb + (size_t)row*8000 + k0 + sub*32 + c8, &Bs[buf][sub][(i*256 + w*64)*8]);
      }
    }
  };

  f32x4 acc[4][4];
  #pragma unroll
  for (int i=0;i<4;i++)
    #pragma unroll
    for (int j=0;j<4;j++) acc[i][j] = (f32x4){0.f,0.f,0.f,0.f};

  stage(s0);
  for (int s=s0; s<s1; s++){
    __syncthreads();
    if (s+1 < s1) stage(s+1);
    const int buf = s&1;
    #pragma unroll
    for (int sub=0; sub<2; sub++){
      bf16x8 af[4], bf[4];
      #pragma unroll
      for (int mi=0;mi<4;mi++) af[mi] = *(const bf16x8*)(&As[buf][sub][(mi*16+l16)*32 + quad*8]);
      #pragma unroll
      for (int ni=0;ni<4;ni++) bf[ni] = *(const bf16x8*)(&Bs[buf][sub][(wn+ni*16+l16)*32 + quad*8]);
      #pragma unroll
      for (int mi=0;mi<4;mi++)
        #pragma unroll
        for (int ni=0;ni<4;ni++)
          acc[mi][ni] = __builtin_amdgcn_mfma_f32_16x16x32_bf16(af[mi], bf[ni], acc[mi][ni], 0,0,0);
    }
  }
  float* dst0 = part + ((size_t)(b*4 + ks)*2048)*256;
  #pragma unroll
  for (int mi=0;mi<4;mi++){
    #pragma unroll
    for (int r=0;r<4;r++){
      int gm = bm + mi*16 + quad*4 + r;
      float* dst = dst0 + (size_t)gm*256;
      #pragma unroll
      for (int ni=0;ni<4;ni++) dst[wn + ni*16 + l16] = acc[mi][ni][r];
    }
  }
}

// ---------------- assemble: out[b,n,:256] = sum_ks part ; out[b,n,256:] = ori[b,n,:]
__global__ void assemble_kernel(const float* __restrict__ part, const float* __restrict__ ori,
                                float* __restrict__ out){
  const int b = blockIdx.y;
  int u = blockIdx.x*256 + threadIdx.x;
  int n = u>>6, c4 = (u&63)*4;
  f32x4 s = (f32x4){0.f,0.f,0.f,0.f};
  #pragma unroll
  for (int ks=0; ks<4; ks++)
    s += *(const f32x4*)(part + ((size_t)(b*4+ks)*2048 + n)*256 + c4);
  float* dst = out + ((size_t)(b*2000+n))*512;
  *(f32x4*)(dst + c4) = s;
  *(f32x4*)(dst + 256 + c4) = *(const f32x4*)(ori + ((size_t)(b*2000+n))*256 + c4);
}

extern "C" void kernel_launch(void* const* d_in, const int* in_sizes, int n_in,
                              void* d_out, int out_size, void* d_ws, size_t ws_size,
                              hipStream_t stream) {
  const float* ed  = (const float*)d_in[0];
  const float* Hm  = (const float*)d_in[1];
  const float* ori = (const float*)d_in[2];
  const float* W1  = (const float*)d_in[3];
  const float* b1  = (const float*)d_in[4];
  const float* W2  = (const float*)d_in[5];
  const float* b2  = (const float*)d_in[6];
  float* out = (float*)d_out;
  char* ws = (char*)d_ws;

  u16* HT    = (u16*)(ws);                 // 4*2048*8000*2 = 131,072,000
  u16* oriT  = (u16*)(ws + 131072000);     // 4,194,304
  u16* W1T   = (u16*)(ws + 135266304);     //   327,680
  u16* W2T   = (u16*)(ws + 135593984);     //   327,680
  u16* edges = (u16*)(ws + 135921664);     // 16,384,000 (reused as EFt)
  u16* H1    = (u16*)(ws + 152305664);     // 40,960,000 (used as part)
  u16* EF    = (u16*)(ws + 193265664);     // 16,384,000
  u16* EFt   = edges;                      // alias: edges dead after m12
  float* part = (float*)H1;                // 33,554,432 <= 40,960,000

  hipLaunchKernelGGL(transpose_f32, dim3(64,8,4), dim3(256), 0, stream,
                     ori, oriT, 2000, 256, 2048, 512000L, 524288L);
  hipLaunchKernelGGL(transpose_f32, dim3(8,4,5), dim3(256), 0, stream,
                     W1, W1T, 256, 128, 256, 32768L, 32768L);
  hipLaunchKernelGGL(transpose_f32, dim3(4,8,5), dim3(256), 0, stream,
                     W2, W2T, 128, 256, 128, 32768L, 32768L);

  hipLaunchKernelGGL(g1_kernel, dim3(125,4), dim3(256), 0, stream, Hm, oriT, edges, HT);
  hipLaunchKernelGGL(m12_kernel, dim3(500), dim3(256), 0, stream,
                     edges, W1T, W2T, b1, b2, ed, EF);
  hipLaunchKernelGGL(transpose_u16, dim3(250,8,4), dim3(256), 0, stream,
                     EF, EFt, 8000, 256, 8000, 2048000L, 2048000L);
  hipLaunchKernelGGL(g3_kernel, dim3(32,4,4), dim3(256), 0, stream, HT, EFt, part);
  hipLaunchKernelGGL(assemble_kernel, dim3(500,4), dim3(256), 0, stream, part, ori, out);

  (void)in_sizes; (void)n_in; (void)ws_size;
}